// Round 2
// baseline (410.877 us; speedup 1.0000x reference)
//
#include <hip/hip_runtime.h>
#include <hip/hip_bf16.h>
#include <stdint.h>

#define IN_F   16080
#define NTREES 64
#define NLEAF  128
#define NCLS   16
#define NBATCH 64
#define M_TOT  (NBATCH*NTREES)     // 4096
#define OUT_HALF (M_TOT*NLEAF)     // 524288

#define BM 64
#define BN 128
#define BK 64                          // 8 chunks of 8 bf16 per row
#define KSPLIT 16
#define NSTEPS ((IN_F + BK - 1)/BK)    // 252 (251 full + 16-elem tail)

typedef __attribute__((ext_vector_type(8))) short short8;   // 8 x bf16
typedef __attribute__((ext_vector_type(4))) float f32x4;

typedef const __attribute__((address_space(1))) uint32_t gu32_t;
typedef __attribute__((address_space(3))) uint32_t su32_t;

// 8 fp32 -> short8 bf16 frag via packed RNE converts
__device__ __forceinline__ short8 cvt8(float4 lo, float4 hi){
  union { short8 s8; __hip_bfloat162 h2[4]; } u;
  u.h2[0] = __float22bfloat162_rn(make_float2(lo.x, lo.y));
  u.h2[1] = __float22bfloat162_rn(make_float2(lo.z, lo.w));
  u.h2[2] = __float22bfloat162_rn(make_float2(hi.x, hi.y));
  u.h2[3] = __float22bfloat162_rn(make_float2(hi.z, hi.w));
  return u.s8;
}

// One-shot W fp32 [128,16080] -> bf16 (RNE, same numerics as the in-loop
// conversion). 8 elems/thread, 2058240 elems = 1005 blocks exactly.
__global__ __launch_bounds__(256)
void wcvt_kernel(const float* __restrict__ W, short* __restrict__ Wb){
  int i = (blockIdx.x * 256 + threadIdx.x) << 3;
  float4 a = *(const float4*)(W + i);
  float4 b = *(const float4*)(W + i + 4);
  *(short8*)(Wb + i) = cvt8(a, b);
}

// ---------------- Fast path: bf16-B, slab split-K (no atomics) -------------
// C = X[4096,16080] * W[128,16080]^T. Each kc writes its partial tile with
// plain stores to accbuf[kc*OUT_HALF + ...]; epilogue reduces the 16 slabs.
// B(=W) is pre-converted bf16; staged via global_load_lds with XOR chunk
// swizzle (8 x 16B chunks/row, c = p ^ (r&7); ds_read aliasing <=2-way = free).
__global__ __launch_bounds__(256, 4)
void gemm_slab_kernel(const float* __restrict__ X,
                      const short* __restrict__ Wb,
                      float* __restrict__ accbuf,
                      const short* __restrict__ zeropage){
  __shared__ __align__(16) short BsH[NLEAF * BK];   // 16 KB bf16, chunk-swizzled

  const int tid = threadIdx.x;
  const int m0  = blockIdx.x * BM;
  const int kc  = blockIdx.y;
  const int s0  = (kc * NSTEPS) / KSPLIT;
  const int s1  = ((kc + 1) * NSTEPS) / KSPLIT;

  const int lane = tid & 63;
  const int wv   = tid >> 6;
  const int wm   = wv & 1;        // 2 m-waves x 2 n-waves
  const int wn   = wv >> 1;
  const int fr   = lane & 15;     // row/col within 16x16 tile
  const int fq   = lane >> 4;     // k-quad

  f32x4 acc[2][4];
  #pragma unroll
  for (int mt = 0; mt < 2; ++mt)
    #pragma unroll
    for (int nt = 0; nt < 4; ++nt) acc[mt][nt] = (f32x4){0.f,0.f,0.f,0.f};

  for (int s = s0; s < s1; ++s){
    const int k0 = s * BK;
    __syncthreads();   // previous tile's ds_read consumers done

    // --- A fragments: direct global -> regs (2 mt x 2 halves x 2 quads) ---
    float4 av[2][2][2];
    #pragma unroll
    for (int mt = 0; mt < 2; ++mt){
      const float* rowp = X + (size_t)(m0 + wm*32 + mt*16 + fr) * IN_F;
      #pragma unroll
      for (int h = 0; h < 2; ++h)
        #pragma unroll
        for (int q = 0; q < 2; ++q){
          int gk = k0 + h*32 + fq*8 + q*4;
          av[mt][h][q] = (gk + 4 <= IN_F) ? *(const float4*)(rowp + gk)
                                          : make_float4(0.f,0.f,0.f,0.f);
        }
    }

    // --- B tile: 4 global_load_lds dwordx4, bf16, swizzled chunk gather ---
    // 1024 chunks (128 rows x 8); LDS linear, global chunk c = p ^ (r&7)
    #pragma unroll
    for (int j = 0; j < 4; ++j){
      int lin = j*256 + tid;
      int r   = lin >> 3;
      int p   = lin & 7;
      int c   = p ^ (r & 7);
      int gk  = k0 + (c << 3);
      const short* gp = (gk + 8 <= IN_F) ? (Wb + (size_t)r * IN_F + gk)
                                         : zeropage;
      __builtin_amdgcn_global_load_lds((gu32_t*)gp, (su32_t*)(BsH + lin*8),
                                       16, 0, 0);
    }

    // convert A while B loads are in flight
    short8 af[2][2];
    #pragma unroll
    for (int mt = 0; mt < 2; ++mt)
      #pragma unroll
      for (int h = 0; h < 2; ++h)
        af[mt][h] = cvt8(av[mt][h][0], av[mt][h][1]);

    __syncthreads();   // drains vmcnt(0): B tile resident in LDS

    // --- compute: 4 nt x 2 halves x 2 mt MFMAs; B frags read bf16-direct ---
    #pragma unroll
    for (int nt = 0; nt < 4; ++nt){
      const int l  = wn*64 + nt*16 + fr;
      const int xw = l & 7;
      const short* rowb = BsH + l*BK;     // 8 chunks of 8 bf16
      #pragma unroll
      for (int h = 0; h < 2; ++h){
        int cc = (((h << 2) + fq) ^ xw) << 3;          // element offset
        short8 bf = *(const short8*)(rowb + cc);       // MFMA-ready, no cvt
        #pragma unroll
        for (int mt = 0; mt < 2; ++mt)
          acc[mt][nt] = __builtin_amdgcn_mfma_f32_16x16x32_bf16(
                            af[mt][h], bf, acc[mt][nt], 0, 0, 0);
      }
    }
  }

  // C/D layout: col = lane&15, row = (lane>>4)*4 + reg  [m89-verified]
  #pragma unroll
  for (int mt = 0; mt < 2; ++mt){
    const int rbase = m0 + wm*32 + mt*16 + fq*4;
    #pragma unroll
    for (int nt = 0; nt < 4; ++nt){
      int col = wn*64 + nt*16 + fr;
      #pragma unroll
      for (int r = 0; r < 4; ++r)
        accbuf[(size_t)kc * OUT_HALF + (size_t)(rbase + r) * NLEAF + col]
            = acc[mt][nt][r];
    }
  }
}

// Epilogue for the slab path: reduce 16 partial slabs, then bias/hardtanh
// + 16-class softmax Gini.
__global__ __launch_bounds__(256)
void epilogue_slab_kernel(const float* __restrict__ slabs,
                          float* __restrict__ out,
                          const float* __restrict__ bias,
                          const float* __restrict__ contrib){
  int idx = blockIdx.x * 256 + threadIdx.x;   // < OUT_HALF
  int l   = idx & (NLEAF - 1);
  int row = idx >> 7;
  int t   = row & (NTREES - 1);

  float s = 0.f;
  #pragma unroll
  for (int kc = 0; kc < KSPLIT; ++kc)
    s += slabs[(size_t)kc * OUT_HALF + idx];
  s += bias[l];
  s = fminf(1.f, fmaxf(-1.f, s));
  out[idx] = s;

  const float4* cp = (const float4*)(contrib + (((size_t)t * NLEAF + l) << 4));
  float4 c0 = cp[0], c1 = cp[1], c2 = cp[2], c3 = cp[3];
  float v[16] = { s*c0.x, s*c0.y, s*c0.z, s*c0.w,
                  s*c1.x, s*c1.y, s*c1.z, s*c1.w,
                  s*c2.x, s*c2.y, s*c2.z, s*c2.w,
                  s*c3.x, s*c3.y, s*c3.z, s*c3.w };
  float m = v[0];
  #pragma unroll
  for (int c = 1; c < 16; ++c) m = fmaxf(m, v[c]);
  float se = 0.f, se2 = 0.f;
  #pragma unroll
  for (int c = 0; c < 16; ++c){
    float e = __expf(v[c] - m);
    se  += e;
    se2 += e * e;
  }
  out[OUT_HALF + idx] = (float)NCLS - se2 / (se * se);
}

// ---------------- Legacy path (harness-verified @429us) --------------------
// Used only when the workspace is too small for slabs+Wb. Needs 256 B of ws.
__global__ __launch_bounds__(256, 4)
void gemm_atomic_kernel(const float* __restrict__ X,
                        const float* __restrict__ Wg,
                        float* __restrict__ accbuf,
                        const float* __restrict__ zeropage){
  __shared__ __align__(16) float BsF[BN * BK];   // 32 KB, fp32, chunk-swizzled

  const int tid = threadIdx.x;
  const int m0  = blockIdx.x * BM;
  const int kc  = blockIdx.y;
  const int s0  = (kc * NSTEPS) / KSPLIT;
  const int s1  = ((kc + 1) * NSTEPS) / KSPLIT;

  const int lane = tid & 63;
  const int wv   = tid >> 6;
  const int wm   = wv & 1;
  const int wn   = wv >> 1;
  const int fr   = lane & 15;
  const int fq   = lane >> 4;

  f32x4 acc[2][4];
  #pragma unroll
  for (int mt = 0; mt < 2; ++mt)
    #pragma unroll
    for (int nt = 0; nt < 4; ++nt) acc[mt][nt] = (f32x4){0.f,0.f,0.f,0.f};

  for (int s = s0; s < s1; ++s){
    const int k0 = s * BK;
    __syncthreads();

    float4 av[2][2][2];
    #pragma unroll
    for (int mt = 0; mt < 2; ++mt){
      const float* rowp = X + (size_t)(m0 + wm*32 + mt*16 + fr) * IN_F;
      #pragma unroll
      for (int h = 0; h < 2; ++h)
        #pragma unroll
        for (int q = 0; q < 2; ++q){
          int gk = k0 + h*32 + fq*8 + q*4;
          av[mt][h][q] = (gk + 4 <= IN_F) ? *(const float4*)(rowp + gk)
                                          : make_float4(0.f,0.f,0.f,0.f);
        }
    }

    #pragma unroll
    for (int j = 0; j < 8; ++j){
      int lin = j*256 + tid;
      int r   = lin >> 4;
      int p   = lin & 15;
      int c   = p ^ (r & 7);
      int gk  = k0 + c*4;
      const float* gp = (gk + 4 <= IN_F) ? (Wg + (size_t)r * IN_F + gk)
                                         : zeropage;
      __builtin_amdgcn_global_load_lds((gu32_t*)gp, (su32_t*)(BsF + lin*4),
                                       16, 0, 0);
    }

    short8 af[2][2];
    #pragma unroll
    for (int mt = 0; mt < 2; ++mt)
      #pragma unroll
      for (int h = 0; h < 2; ++h)
        af[mt][h] = cvt8(av[mt][h][0], av[mt][h][1]);

    __syncthreads();

    #pragma unroll
    for (int nt = 0; nt < 4; ++nt){
      const int l  = wn*64 + nt*16 + fr;
      const int xw = l & 7;
      const float* rowb = BsF + l*64;
      #pragma unroll
      for (int h = 0; h < 2; ++h){
        int c0 = h*8 + fq*2;
        float4 b0 = *(const float4*)(rowb + ((c0    ) ^ xw)*4);
        float4 b1 = *(const float4*)(rowb + ((c0 + 1) ^ xw)*4);
        short8 bf = cvt8(b0, b1);
        #pragma unroll
        for (int mt = 0; mt < 2; ++mt)
          acc[mt][nt] = __builtin_amdgcn_mfma_f32_16x16x32_bf16(
                            af[mt][h], bf, acc[mt][nt], 0, 0, 0);
      }
    }
  }

  #pragma unroll
  for (int mt = 0; mt < 2; ++mt){
    const int rbase = m0 + wm*32 + mt*16 + fq*4;
    #pragma unroll
    for (int nt = 0; nt < 4; ++nt){
      int col = wn*64 + nt*16 + fr;
      #pragma unroll
      for (int r = 0; r < 4; ++r)
        atomicAdd(&accbuf[(size_t)(rbase + r) * NLEAF + col], acc[mt][nt][r]);
    }
  }
}

__global__ __launch_bounds__(256)
void epilogue_inplace_kernel(float* __restrict__ out,
                             const float* __restrict__ bias,
                             const float* __restrict__ contrib){
  int idx = blockIdx.x * 256 + threadIdx.x;   // < OUT_HALF
  int l   = idx & (NLEAF - 1);
  int row = idx >> 7;
  int t   = row & (NTREES - 1);

  float s = out[idx] + bias[l];
  s = fminf(1.f, fmaxf(-1.f, s));
  out[idx] = s;

  const float4* cp = (const float4*)(contrib + (((size_t)t * NLEAF + l) << 4));
  float4 c0 = cp[0], c1 = cp[1], c2 = cp[2], c3 = cp[3];
  float v[16] = { s*c0.x, s*c0.y, s*c0.z, s*c0.w,
                  s*c1.x, s*c1.y, s*c1.z, s*c1.w,
                  s*c2.x, s*c2.y, s*c2.z, s*c2.w,
                  s*c3.x, s*c3.y, s*c3.z, s*c3.w };
  float m = v[0];
  #pragma unroll
  for (int c = 1; c < 16; ++c) m = fmaxf(m, v[c]);
  float se = 0.f, se2 = 0.f;
  #pragma unroll
  for (int c = 0; c < 16; ++c){
    float e = __expf(v[c] - m);
    se  += e;
    se2 += e * e;
  }
  out[OUT_HALF + idx] = (float)NCLS - se2 / (se * se);
}

extern "C" void kernel_launch(void* const* d_in, const int* in_sizes, int n_in,
                              void* d_out, int out_size, void* d_ws, size_t ws_size,
                              hipStream_t stream){
  const float* X       = (const float*)d_in[0];   // [64,64,16080]
  const float* Wg      = (const float*)d_in[1];   // [128,16080]
  const float* bias    = (const float*)d_in[2];   // [128]
  const float* contrib = (const float*)d_in[3];   // [64,128,16]
  float* out = (float*)d_out;

  const size_t SLAB_BYTES = (size_t)KSPLIT * OUT_HALF * sizeof(float); // 33.55 MB
  const size_t WB_BYTES   = (size_t)NLEAF * IN_F * sizeof(short);      // 4.12 MB
  char* ws = (char*)d_ws;
  const int WCVT_BLOCKS = (NLEAF * IN_F) / (256 * 8);                  // 1005

  dim3 g1(M_TOT / BM, KSPLIT);

  if (ws_size >= SLAB_BYTES + WB_BYTES + 256){
    // ws layout: [16 slabs 33.55MB][W_bf16 4.12MB][zero page 256B]
    float* slabs = (float*)ws;
    short* Wb    = (short*)(ws + SLAB_BYTES);
    short* zp    = (short*)(ws + SLAB_BYTES + WB_BYTES);
    hipMemsetAsync(zp, 0, 256, stream);
    wcvt_kernel<<<WCVT_BLOCKS, 256, 0, stream>>>(Wg, Wb);
    gemm_slab_kernel<<<g1, 256, 0, stream>>>(X, Wb, slabs, zp);
    epilogue_slab_kernel<<<OUT_HALF / 256, 256, 0, stream>>>(slabs, out, bias, contrib);
  } else {
    // legacy harness-verified path: fp32 W staged per-step, atomic split-K.
    // Needs only a 256 B zero page in ws.
    hipMemsetAsync(out, 0, (size_t)OUT_HALF * sizeof(float), stream);
    hipMemsetAsync(ws, 0, 256, stream);
    gemm_atomic_kernel<<<g1, 256, 0, stream>>>(X, Wg, out, (const float*)ws);
    epilogue_inplace_kernel<<<OUT_HALF / 256, 256, 0, stream>>>(out, bias, contrib);
  }
}

// Round 4
// 400.494 us; speedup vs baseline: 1.0259x; 1.0259x over previous
//
#include <hip/hip_runtime.h>
#include <hip/hip_bf16.h>
#include <stdint.h>

#define IN_F   16080
#define NTREES 64
#define NLEAF  128
#define NCLS   16
#define NBATCH 64
#define M_TOT  (NBATCH*NTREES)     // 4096
#define OUT_HALF (M_TOT*NLEAF)     // 524288

#define BM 64
#define BN 128
#define BK 64                          // 8 chunks of 8 bf16 per row
#define KSPLIT 16
#define NSTEPS ((IN_F + BK - 1)/BK)    // 252 (251 full + 16-elem tail)

typedef __attribute__((ext_vector_type(8))) short short8;   // 8 x bf16
typedef __attribute__((ext_vector_type(4))) float f32x4;

typedef const __attribute__((address_space(1))) uint32_t gu32_t;
typedef __attribute__((address_space(3))) uint32_t su32_t;

// 8 fp32 -> short8 bf16 frag via packed RNE converts
__device__ __forceinline__ short8 cvt8(float4 lo, float4 hi){
  union { short8 s8; __hip_bfloat162 h2[4]; } u;
  u.h2[0] = __float22bfloat162_rn(make_float2(lo.x, lo.y));
  u.h2[1] = __float22bfloat162_rn(make_float2(lo.z, lo.w));
  u.h2[2] = __float22bfloat162_rn(make_float2(hi.x, hi.y));
  u.h2[3] = __float22bfloat162_rn(make_float2(hi.z, hi.w));
  return u.s8;
}

// One-shot W fp32 [128,16080] -> bf16 (RNE, same numerics as the in-loop
// conversion). 8 elems/thread, 2058240 elems = 1005 blocks exactly.
__global__ __launch_bounds__(256)
void wcvt_kernel(const float* __restrict__ W, short* __restrict__ Wb){
  int i = (blockIdx.x * 256 + threadIdx.x) << 3;
  float4 a = *(const float4*)(W + i);
  float4 b = *(const float4*)(W + i + 4);
  *(short8*)(Wb + i) = cvt8(a, b);
}

// ---------------- Fast path: bf16-B, slab split-K, 2-deep pipeline ---------
// C = X[4096,16080] * W[128,16080]^T. Each kc writes its partial tile with
// plain stores to accbuf[kc*OUT_HALF + ...]; epilogue reduces the 16 slabs.
//
// Pipeline (T3-min + counted vmcnt, raw barriers — no __syncthreads drain):
//   prologue: STAGE_B(buf0, s0); LOAD_A(av, s0)            // 12 vm ops
//   iter s:   STAGE_B(buf[nxt], s+1)                       // +4 vm ops
//             s_waitcnt vmcnt(4)   // newest 4 = this stage; retires prev 12
//             s_barrier            // buf[cur] resident for all waves
//             af = cvt8(av)        // frees av
//             LOAD_A(av, s+1)      // overlaps with MFMA phase below
//             ds_read buf[cur] -> 16 MFMA
//             s_barrier            // readers of buf[cur] done -> safe to
//                                  // overwrite it at iter s+2's STAGE
// vmcnt(4) is correct even when tail-step prefetch elides some A-loads:
// the 4 ops allowed to remain outstanding are always the NEWEST 4 (this
// iter's B-stage), and vmcnt retires strictly in issue order.
__global__ __launch_bounds__(256, 4)
void gemm_slab_kernel(const float* __restrict__ X,
                      const short* __restrict__ Wb,
                      float* __restrict__ accbuf,
                      const short* __restrict__ zeropage){
  __shared__ __align__(16) short BsH[2][NLEAF * BK];   // 2 x 16 KB, chunk-swizzled

  const int tid = threadIdx.x;
  const int m0  = blockIdx.x * BM;
  const int kc  = blockIdx.y;
  const int s0  = (kc * NSTEPS) / KSPLIT;
  const int s1  = ((kc + 1) * NSTEPS) / KSPLIT;

  const int lane = tid & 63;
  const int wv   = tid >> 6;
  const int wm   = wv & 1;        // 2 m-waves x 2 n-waves
  const int wn   = wv >> 1;
  const int fr   = lane & 15;     // row/col within 16x16 tile
  const int fq   = lane >> 4;     // k-quad

  f32x4 acc[2][4];
  #pragma unroll
  for (int mt = 0; mt < 2; ++mt)
    #pragma unroll
    for (int nt = 0; nt < 4; ++nt) acc[mt][nt] = (f32x4){0.f,0.f,0.f,0.f};

  float4 av[2][2][2];
  const float* arow[2];
  arow[0] = X + (size_t)(m0 + wm*32 + 0*16 + fr) * IN_F;
  arow[1] = X + (size_t)(m0 + wm*32 + 1*16 + fr) * IN_F;

  // --- prologue: stage step s0 ---
  {
    const int k0 = s0 * BK;
    #pragma unroll
    for (int j = 0; j < 4; ++j){
      int lin = j*256 + tid;              // lin = (row<<3)|p
      int r   = lin >> 3;
      int c   = (lin & 7) ^ (r & 7);
      int gk  = k0 + (c << 3);
      const short* gp = (gk + 8 <= IN_F) ? (Wb + (size_t)r * IN_F + gk)
                                         : zeropage;
      __builtin_amdgcn_global_load_lds((gu32_t*)gp, (su32_t*)(&BsH[0][0] + lin*8),
                                       16, 0, 0);
    }
    #pragma unroll
    for (int mt = 0; mt < 2; ++mt)
      #pragma unroll
      for (int h = 0; h < 2; ++h)
        #pragma unroll
        for (int q = 0; q < 2; ++q){
          int gk = k0 + h*32 + fq*8 + q*4;
          av[mt][h][q] = (gk + 4 <= IN_F) ? *(const float4*)(arow[mt] + gk)
                                          : make_float4(0.f,0.f,0.f,0.f);
        }
  }

  for (int s = s0; s < s1; ++s){
    const int par = (s - s0) & 1;
    short* bcur = &BsH[par][0];
    short* bnxt = &BsH[par ^ 1][0];

    // --- stage B for step s+1 (4 gload_lds; OOB -> zeropage) ---
    {
      const int k1 = (s + 1) * BK;
      #pragma unroll
      for (int j = 0; j < 4; ++j){
        int lin = j*256 + tid;
        int r   = lin >> 3;
        int c   = (lin & 7) ^ (r & 7);
        int gk  = k1 + (c << 3);
        const short* gp = (gk + 8 <= IN_F) ? (Wb + (size_t)r * IN_F + gk)
                                           : zeropage;
        __builtin_amdgcn_global_load_lds((gu32_t*)gp, (su32_t*)(bnxt + lin*8),
                                         16, 0, 0);
      }
    }

    // wait for step-s data (prev iter's 12 ops), keep this stage in flight
    asm volatile("s_waitcnt vmcnt(4)" ::: "memory");
    __builtin_amdgcn_s_barrier();

    // convert A for step s (frees av), then prefetch A for step s+1
    short8 af[2][2];
    #pragma unroll
    for (int mt = 0; mt < 2; ++mt)
      #pragma unroll
      for (int h = 0; h < 2; ++h)
        af[mt][h] = cvt8(av[mt][h][0], av[mt][h][1]);

    {
      const int k1 = (s + 1) * BK;
      #pragma unroll
      for (int mt = 0; mt < 2; ++mt)
        #pragma unroll
        for (int h = 0; h < 2; ++h)
          #pragma unroll
          for (int q = 0; q < 2; ++q){
            int gk = k1 + h*32 + fq*8 + q*4;
            av[mt][h][q] = (gk + 4 <= IN_F) ? *(const float4*)(arow[mt] + gk)
                                            : make_float4(0.f,0.f,0.f,0.f);
          }
    }

    // --- compute: 4 nt x 2 halves x 2 mt MFMAs; B frags read bf16-direct ---
    #pragma unroll
    for (int nt = 0; nt < 4; ++nt){
      const int l  = wn*64 + nt*16 + fr;
      const int xw = l & 7;
      const short* rowb = bcur + l*BK;     // 8 chunks of 8 bf16
      #pragma unroll
      for (int h = 0; h < 2; ++h){
        int cc = (((h << 2) + fq) ^ xw) << 3;          // element offset
        short8 bf = *(const short8*)(rowb + cc);       // MFMA-ready, no cvt
        #pragma unroll
        for (int mt = 0; mt < 2; ++mt)
          acc[mt][nt] = __builtin_amdgcn_mfma_f32_16x16x32_bf16(
                            af[mt][h], bf, acc[mt][nt], 0, 0, 0);
      }
    }

    // readers of bcur done (ds_reads retired before their MFMAs issued);
    // next iter stages into bcur's partner; bcur itself reused at s+2.
    __builtin_amdgcn_s_barrier();
  }

  // C/D layout: col = lane&15, row = (lane>>4)*4 + reg  [m89-verified]
  #pragma unroll
  for (int mt = 0; mt < 2; ++mt){
    const int rbase = m0 + wm*32 + mt*16 + fq*4;
    #pragma unroll
    for (int nt = 0; nt < 4; ++nt){
      int col = wn*64 + nt*16 + fr;
      #pragma unroll
      for (int r = 0; r < 4; ++r)
        accbuf[(size_t)kc * OUT_HALF + (size_t)(rbase + r) * NLEAF + col]
            = acc[mt][nt][r];
    }
  }
}

// Epilogue for the slab path: reduce 16 partial slabs, then bias/hardtanh
// + 16-class softmax Gini.
__global__ __launch_bounds__(256)
void epilogue_slab_kernel(const float* __restrict__ slabs,
                          float* __restrict__ out,
                          const float* __restrict__ bias,
                          const float* __restrict__ contrib){
  int idx = blockIdx.x * 256 + threadIdx.x;   // < OUT_HALF
  int l   = idx & (NLEAF - 1);
  int row = idx >> 7;
  int t   = row & (NTREES - 1);

  float s = 0.f;
  #pragma unroll
  for (int kc = 0; kc < KSPLIT; ++kc)
    s += slabs[(size_t)kc * OUT_HALF + idx];
  s += bias[l];
  s = fminf(1.f, fmaxf(-1.f, s));
  out[idx] = s;

  const float4* cp = (const float4*)(contrib + (((size_t)t * NLEAF + l) << 4));
  float4 c0 = cp[0], c1 = cp[1], c2 = cp[2], c3 = cp[3];
  float v[16] = { s*c0.x, s*c0.y, s*c0.z, s*c0.w,
                  s*c1.x, s*c1.y, s*c1.z, s*c1.w,
                  s*c2.x, s*c2.y, s*c2.z, s*c2.w,
                  s*c3.x, s*c3.y, s*c3.z, s*c3.w };
  float m = v[0];
  #pragma unroll
  for (int c = 1; c < 16; ++c) m = fmaxf(m, v[c]);
  float se = 0.f, se2 = 0.f;
  #pragma unroll
  for (int c = 0; c < 16; ++c){
    float e = __expf(v[c] - m);
    se  += e;
    se2 += e * e;
  }
  out[OUT_HALF + idx] = (float)NCLS - se2 / (se * se);
}

// ---------------- Legacy path (harness-verified @429us) --------------------
// Used only when the workspace is too small for slabs+Wb. Needs 256 B of ws.
__global__ __launch_bounds__(256, 4)
void gemm_atomic_kernel(const float* __restrict__ X,
                        const float* __restrict__ Wg,
                        float* __restrict__ accbuf,
                        const float* __restrict__ zeropage){
  __shared__ __align__(16) float BsF[BN * BK];   // 32 KB, fp32, chunk-swizzled

  const int tid = threadIdx.x;
  const int m0  = blockIdx.x * BM;
  const int kc  = blockIdx.y;
  const int s0  = (kc * NSTEPS) / KSPLIT;
  const int s1  = ((kc + 1) * NSTEPS) / KSPLIT;

  const int lane = tid & 63;
  const int wv   = tid >> 6;
  const int wm   = wv & 1;
  const int wn   = wv >> 1;
  const int fr   = lane & 15;
  const int fq   = lane >> 4;

  f32x4 acc[2][4];
  #pragma unroll
  for (int mt = 0; mt < 2; ++mt)
    #pragma unroll
    for (int nt = 0; nt < 4; ++nt) acc[mt][nt] = (f32x4){0.f,0.f,0.f,0.f};

  for (int s = s0; s < s1; ++s){
    const int k0 = s * BK;
    __syncthreads();

    float4 av[2][2][2];
    #pragma unroll
    for (int mt = 0; mt < 2; ++mt){
      const float* rowp = X + (size_t)(m0 + wm*32 + mt*16 + fr) * IN_F;
      #pragma unroll
      for (int h = 0; h < 2; ++h)
        #pragma unroll
        for (int q = 0; q < 2; ++q){
          int gk = k0 + h*32 + fq*8 + q*4;
          av[mt][h][q] = (gk + 4 <= IN_F) ? *(const float4*)(rowp + gk)
                                          : make_float4(0.f,0.f,0.f,0.f);
        }
    }

    #pragma unroll
    for (int j = 0; j < 8; ++j){
      int lin = j*256 + tid;
      int r   = lin >> 4;
      int p   = lin & 15;
      int c   = p ^ (r & 7);
      int gk  = k0 + c*4;
      const float* gp = (gk + 4 <= IN_F) ? (Wg + (size_t)r * IN_F + gk)
                                         : zeropage;
      __builtin_amdgcn_global_load_lds((gu32_t*)gp, (su32_t*)(BsF + lin*4),
                                       16, 0, 0);
    }

    short8 af[2][2];
    #pragma unroll
    for (int mt = 0; mt < 2; ++mt)
      #pragma unroll
      for (int h = 0; h < 2; ++h)
        af[mt][h] = cvt8(av[mt][h][0], av[mt][h][1]);

    __syncthreads();

    #pragma unroll
    for (int nt = 0; nt < 4; ++nt){
      const int l  = wn*64 + nt*16 + fr;
      const int xw = l & 7;
      const float* rowb = BsF + l*64;
      #pragma unroll
      for (int h = 0; h < 2; ++h){
        int c0 = h*8 + fq*2;
        float4 b0 = *(const float4*)(rowb + ((c0    ) ^ xw)*4);
        float4 b1 = *(const float4*)(rowb + ((c0 + 1) ^ xw)*4);
        short8 bf = cvt8(b0, b1);
        #pragma unroll
        for (int mt = 0; mt < 2; ++mt)
          acc[mt][nt] = __builtin_amdgcn_mfma_f32_16x16x32_bf16(
                            af[mt][h], bf, acc[mt][nt], 0, 0, 0);
      }
    }
  }

  #pragma unroll
  for (int mt = 0; mt < 2; ++mt){
    const int rbase = m0 + wm*32 + mt*16 + fq*4;
    #pragma unroll
    for (int nt = 0; nt < 4; ++nt){
      int col = wn*64 + nt*16 + fr;
      #pragma unroll
      for (int r = 0; r < 4; ++r)
        atomicAdd(&accbuf[(size_t)(rbase + r) * NLEAF + col], acc[mt][nt][r]);
    }
  }
}

__global__ __launch_bounds__(256)
void epilogue_inplace_kernel(float* __restrict__ out,
                             const float* __restrict__ bias,
                             const float* __restrict__ contrib){
  int idx = blockIdx.x * 256 + threadIdx.x;   // < OUT_HALF
  int l   = idx & (NLEAF - 1);
  int row = idx >> 7;
  int t   = row & (NTREES - 1);

  float s = out[idx] + bias[l];
  s = fminf(1.f, fmaxf(-1.f, s));
  out[idx] = s;

  const float4* cp = (const float4*)(contrib + (((size_t)t * NLEAF + l) << 4));
  float4 c0 = cp[0], c1 = cp[1], c2 = cp[2], c3 = cp[3];
  float v[16] = { s*c0.x, s*c0.y, s*c0.z, s*c0.w,
                  s*c1.x, s*c1.y, s*c1.z, s*c1.w,
                  s*c2.x, s*c2.y, s*c2.z, s*c2.w,
                  s*c3.x, s*c3.y, s*c3.z, s*c3.w };
  float m = v[0];
  #pragma unroll
  for (int c = 1; c < 16; ++c) m = fmaxf(m, v[c]);
  float se = 0.f, se2 = 0.f;
  #pragma unroll
  for (int c = 0; c < 16; ++c){
    float e = __expf(v[c] - m);
    se  += e;
    se2 += e * e;
  }
  out[OUT_HALF + idx] = (float)NCLS - se2 / (se * se);
}

extern "C" void kernel_launch(void* const* d_in, const int* in_sizes, int n_in,
                              void* d_out, int out_size, void* d_ws, size_t ws_size,
                              hipStream_t stream){
  const float* X       = (const float*)d_in[0];   // [64,64,16080]
  const float* Wg      = (const float*)d_in[1];   // [128,16080]
  const float* bias    = (const float*)d_in[2];   // [128]
  const float* contrib = (const float*)d_in[3];   // [64,128,16]
  float* out = (float*)d_out;

  const size_t SLAB_BYTES = (size_t)KSPLIT * OUT_HALF * sizeof(float); // 33.55 MB
  const size_t WB_BYTES   = (size_t)NLEAF * IN_F * sizeof(short);      // 4.12 MB
  char* ws = (char*)d_ws;
  const int WCVT_BLOCKS = (NLEAF * IN_F) / (256 * 8);                  // 1005

  dim3 g1(M_TOT / BM, KSPLIT);

  if (ws_size >= SLAB_BYTES + WB_BYTES + 256){
    // ws layout: [16 slabs 33.55MB][W_bf16 4.12MB][zero page 256B]
    float* slabs = (float*)ws;
    short* Wb    = (short*)(ws + SLAB_BYTES);
    short* zp    = (short*)(ws + SLAB_BYTES + WB_BYTES);
    hipMemsetAsync(zp, 0, 256, stream);
    wcvt_kernel<<<WCVT_BLOCKS, 256, 0, stream>>>(Wg, Wb);
    gemm_slab_kernel<<<g1, 256, 0, stream>>>(X, Wb, slabs, zp);
    epilogue_slab_kernel<<<OUT_HALF / 256, 256, 0, stream>>>(slabs, out, bias, contrib);
  } else {
    // legacy harness-verified path: fp32 W staged per-step, atomic split-K.
    // Needs only a 256 B zero page in ws.
    hipMemsetAsync(out, 0, (size_t)OUT_HALF * sizeof(float), stream);
    hipMemsetAsync(ws, 0, 256, stream);
    gemm_atomic_kernel<<<g1, 256, 0, stream>>>(X, Wg, out, (const float*)ws);
    epilogue_inplace_kernel<<<OUT_HALF / 256, 256, 0, stream>>>(out, bias, contrib);
  }
}